// Round 20
// baseline (108.193 us; speedup 1.0000x reference)
//
#include <hip/hip_runtime.h>
#include <hip/hip_bf16.h>

#define B_DIM 512
#define D_DIM 256
#define C_DIM 100000
#define LAMB 1000.0f
#define NPANEL 391            // ceil(C/256)

using bf16x8 = __attribute__((ext_vector_type(8))) short;
using f32x4  = __attribute__((ext_vector_type(4))) float;

__device__ __forceinline__ short f2bf(float f) {
  unsigned u = __builtin_bit_cast(unsigned, f);
  u += 0x7FFFu + ((u >> 16) & 1u);      // round-to-nearest-even
  return (short)(u >> 16);
}

// async global->LDS, 16B per lane; LDS dest = wave-uniform base + lane*16
__device__ __forceinline__ void gload_lds16(const void* g, void* l) {
  __builtin_amdgcn_global_load_lds(
      (__attribute__((address_space(1))) void*)g,
      (__attribute__((address_space(3))) void*)l, 16, 0, 0);
}

// Kernel 1: xlen per row + bf16 x, pre-swizzled (byte ^= (row&7)<<4).
__global__ __launch_bounds__(256) void prep_x(const float* __restrict__ x,
                                              unsigned short* __restrict__ x_swz,
                                              float* __restrict__ xlen) {
  int wv = threadIdx.x >> 6, lane = threadIdx.x & 63;
  int row = blockIdx.x * 4 + wv;
  float4 v = *(const float4*)(x + row * D_DIM + lane * 4);
  float ss = v.x * v.x + v.y * v.y + v.z * v.z + v.w * v.w;
#pragma unroll
  for (int m = 1; m < 64; m <<= 1) ss += __shfl_xor(ss, m);
  if (lane == 0) xlen[row] = sqrtf(ss);
  ushort4 u;
  u.x = (unsigned short)f2bf(v.x);
  u.y = (unsigned short)f2bf(v.y);
  u.z = (unsigned short)f2bf(v.z);
  u.w = (unsigned short)f2bf(v.w);
  int byteoff = row * 512 + ((lane * 8) ^ ((row & 7) << 4));
  *(ushort4*)((char*)x_swz + byteoff) = u;
}

// Kernel 2: r18 structure widened to 256-col x 256-row blocks (8 waves).
// r19 isolated the residual wall: with W reads fully L3-resident the nt
// write stream still capped at ~3.2 TB/s -> run LENGTH is the lever.
// Store-run length = block column width: 128 cols (r18) gave 512B runs;
// 256 cols gives ONE 1KB contiguous run per store instruction (64 lanes x
// 16B), >= HBM page granule, halving row activations per byte.
// Everything else is the proven r18 recipe: in-kernel phase-1 (32 cols per
// wave, same code), swizzled x staging double-buffered, transpose tb
// (32x260, pad -> 2-way write conflicts = free), nt stores, lgkm-only
// transpose barrier + counted vmcnt(4) end-of-chunk barrier.
__global__ __launch_bounds__(512) void gemm_bf16(
    const float* __restrict__ W, const unsigned short* __restrict__ xb,
    const float* __restrict__ xlen, float* __restrict__ out) {
  __shared__ unsigned short xs[2][32 * 256];   // 32 KB (swizzled x rows)
  __shared__ float tb[32 * 260];               // 33.3 KB transpose buffer
  __shared__ float xlen_s[256];                // this block's 256 rows

  const int tid = threadIdx.x;
  const int lane = tid & 63, wv = tid >> 6;
  const int l15 = lane & 15, g = lane >> 4;

  const int bid = blockIdx.x;
  const int panel = bid >> 1, half = bid & 1;
  const int bcol0 = panel * 256;
  const int bn0 = bcol0 + wv * 32;             // this wave's 32 cols
  const int row0 = half * 256;                 // this block's 256 rows

  if (tid < 256) xlen_s[tid] = xlen[row0 + tid];

  // prologue: stage chunk 0 (rows row0..row0+31; 16 KB; 2 gloads/thread)
#pragma unroll
  for (int i = 0; i < 2; ++i)
    gload_lds16((const char*)xb + row0 * 512 + i * 8192 + tid * 16,
                (char*)xs[0] + i * 8192 + wv * 1024);

  // ---- Phase 1: W cols -> A-frags (bf16) + inv_wlen (fp32), r4-proven ----
  // A-frag: lane holds A[row][k], row = lane&15 -> W-col, k = kg*32+g*8+j.
  bf16x8 fw[2][8];
  float invw4[2][4];   // inv_wlen for W-col = bn0 + it*16 + g*4 + r
#pragma unroll
  for (int it = 0; it < 2; ++it) {
    int col = bn0 + it * 16 + l15;
    if (col >= C_DIM) col = C_DIM - 1;        // clamp; stores are guarded
    const float* wr = W + (size_t)col * D_DIM + g * 8;
    float ss = 0.f;
#pragma unroll
    for (int kg = 0; kg < 8; ++kg) {
      float4 a = *(const float4*)(wr + kg * 32);
      float4 b = *(const float4*)(wr + kg * 32 + 4);
      ss += a.x * a.x + a.y * a.y + a.z * a.z + a.w * a.w
          + b.x * b.x + b.y * b.y + b.z * b.z + b.w * b.w;
      bf16x8 f;
      f[0] = f2bf(a.x); f[1] = f2bf(a.y); f[2] = f2bf(a.z); f[3] = f2bf(a.w);
      f[4] = f2bf(b.x); f[5] = f2bf(b.y); f[6] = f2bf(b.z); f[7] = f2bf(b.w);
      fw[it][kg] = f;
    }
    ss += __shfl_xor(ss, 16);                 // reduce across the 4 g-groups
    ss += __shfl_xor(ss, 32);
    float iw = 1.0f / sqrtf(ss);              // lane l15 holds col bn0+it*16+l15
#pragma unroll
    for (int r = 0; r < 4; ++r) invw4[it][r] = __shfl(iw, g * 4 + r);
  }

  __syncthreads();                            // chunk 0 staged (full drain ok)

  // ---- Main loop: 8 chunks of 32 rows ----
  int buf = 0;
  for (int chunk = 0; chunk < 8; ++chunk) {
    if (chunk < 7) {                          // prefetch next chunk
#pragma unroll
      for (int i = 0; i < 2; ++i)
        gload_lds16((const char*)xb + (row0 + (chunk + 1) * 32) * 512 +
                        i * 8192 + tid * 16,
                    (char*)xs[buf ^ 1] + i * 8192 + wv * 1024);
    }
    __builtin_amdgcn_sched_barrier(0);        // gloads stay above

    // compute the 32-row chunk (acc: 16 regs, static-indexed)
    f32x4 acc[2][2] = {};                     // [jtl][it]
#pragma unroll
    for (int jtl = 0; jtl < 2; ++jtl) {
      const char* xp = (const char*)xs[buf] + (jtl * 16 + l15) * 512;
      const int swz = (l15 & 7) << 4;
      bf16x8 fx[8];
#pragma unroll
      for (int kg = 0; kg < 8; ++kg)
        fx[kg] = *(const bf16x8*)(xp + ((kg * 64 + g * 16) ^ swz));
#pragma unroll
      for (int kg = 0; kg < 8; ++kg) {
        acc[jtl][0] = __builtin_amdgcn_mfma_f32_16x16x32_bf16(fw[0][kg], fx[kg], acc[jtl][0], 0, 0, 0);
        acc[jtl][1] = __builtin_amdgcn_mfma_f32_16x16x32_bf16(fw[1][kg], fx[kg], acc[jtl][1], 0, 0, 0);
      }
    }

    // epilogue math + transpose write: tb[lrow][wv*32 + it*16 + g*4]
#pragma unroll
    for (int jtl = 0; jtl < 2; ++jtl) {
      const int lrow = jtl * 16 + l15;
      const float xl = xlen_s[chunk * 32 + lrow];
#pragma unroll
      for (int it = 0; it < 2; ++it) {
        float4 v;
        v.x = fminf(fmaxf(acc[jtl][it][0] * invw4[it][0], -xl), xl);
        v.y = fminf(fmaxf(acc[jtl][it][1] * invw4[it][1], -xl), xl);
        v.z = fminf(fmaxf(acc[jtl][it][2] * invw4[it][2], -xl), xl);
        v.w = fminf(fmaxf(acc[jtl][it][3] * invw4[it][3], -xl), xl);
        *(float4*)&tb[lrow * 260 + wv * 32 + it * 16 + g * 4] = v;
      }
    }

    // barrier A: LDS-only — prefetch gloads stay in flight (no vmcnt drain)
    asm volatile("s_waitcnt lgkmcnt(0)" ::: "memory");
    __builtin_amdgcn_s_barrier();

    // read back row-contiguous; each store instruction = ONE 1KB run
    // (wave wv owns row p*8+wv; 64 lanes x 16B cover 256 cols contiguous)
    {
      const int gcol = bcol0 + lane * 4;
      const bool ok = gcol < C_DIM;           // C%4==0 -> float4 all-or-nothing
#pragma unroll
      for (int p = 0; p < 4; ++p) {
        const int lrow = p * 8 + wv;
        f32x4 v = *(const f32x4*)&tb[lrow * 260 + lane * 4];
        if (ok)
          __builtin_nontemporal_store(
              v, (f32x4*)(out + (size_t)(row0 + chunk * 32 + lrow) * C_DIM + gcol));
      }
    }

    // end-of-chunk: counted wait — retire the 2 prefetch gloads (oldest),
    // leave this chunk's 4 nt stores in flight. No barrier after last chunk.
    if (chunk < 7) {
      __builtin_amdgcn_sched_barrier(0);      // stores stay above
      asm volatile("s_waitcnt vmcnt(4)" ::: "memory");
      __builtin_amdgcn_s_barrier();
      __builtin_amdgcn_sched_barrier(0);
    }
    buf ^= 1;
  }
}

// Kernel 3: exact fp32 recompute of the 512 label positions (margin math).
__global__ __launch_bounds__(256) void fix_labels(const float* __restrict__ x,
                                                  const float* __restrict__ W,
                                                  const int* __restrict__ y,
                                                  float* __restrict__ out) {
  int wv = threadIdx.x >> 6, lane = threadIdx.x & 63;
  int b = blockIdx.x * 4 + wv;
  int c = y[b];
  float4 wvv = *(const float4*)(W + (size_t)c * D_DIM + lane * 4);
  float4 xv  = *(const float4*)(x + b * D_DIM + lane * 4);
  float dt = wvv.x * xv.x + wvv.y * xv.y + wvv.z * xv.z + wvv.w * xv.w;
  float sw = wvv.x * wvv.x + wvv.y * wvv.y + wvv.z * wvv.z + wvv.w * wvv.w;
  float sx = xv.x * xv.x + xv.y * xv.y + xv.z * xv.z + xv.w * xv.w;
#pragma unroll
  for (int m = 1; m < 64; m <<= 1) {
    dt += __shfl_xor(dt, m);
    sw += __shfl_xor(sw, m);
    sx += __shfl_xor(sx, m);
  }
  if (lane == 0) {
    float xl = sqrtf(sx), wl = sqrtf(sw);
    float cth = dt / (xl * wl);
    cth = fminf(fmaxf(cth, -1.f), 1.f);
    float c2 = cth * cth;
    float cm = 8.f * c2 * c2 - 8.f * c2 + 1.f;          // cos(4t) Chebyshev
    float k = floorf(4.0f * acosf(cth) / 3.14159265358979323846f);
    float sgn = (((int)k) & 1) ? -1.f : 1.f;
    float phi = sgn * cm - 2.f * k;
    float feat = cth * xl;
    out[(size_t)b * C_DIM + c] = feat + (phi * xl - feat) / (1.f + LAMB);
  }
}

extern "C" void kernel_launch(void* const* d_in, const int* in_sizes, int n_in,
                              void* d_out, int out_size, void* d_ws, size_t ws_size,
                              hipStream_t stream) {
  const float* x = (const float*)d_in[0];
  const float* W = (const float*)d_in[1];
  const int*   y = (const int*)d_in[2];
  float* out = (float*)d_out;

  unsigned short* xb = (unsigned short*)d_ws;                    // 256 KB (swizzled bf16 x)
  float* xlen = (float*)((char*)d_ws + B_DIM * D_DIM * 2);       // 2 KB

  prep_x<<<B_DIM / 4, 256, 0, stream>>>(x, xb, xlen);
  gemm_bf16<<<NPANEL * 2, 512, 0, stream>>>(W, xb, xlen, out);   // 782 blocks
  fix_labels<<<B_DIM / 4, 256, 0, stream>>>(x, W, y, out);
}

// Round 21
// 77.773 us; speedup vs baseline: 1.3911x; 1.3911x over previous
//
#include <hip/hip_runtime.h>
#include <hip/hip_bf16.h>

#define B_DIM 512
#define D_DIM 256
#define C_DIM 100000
#define LAMB 1000.0f

using bf16x8 = __attribute__((ext_vector_type(8))) short;
using f32x4  = __attribute__((ext_vector_type(4))) float;

__device__ __forceinline__ short f2bf(float f) {
  unsigned u = __builtin_bit_cast(unsigned, f);
  u += 0x7FFFu + ((u >> 16) & 1u);      // round-to-nearest-even
  return (short)(u >> 16);
}

// async global->LDS, 16B per lane; LDS dest = wave-uniform base + lane*16
__device__ __forceinline__ void gload_lds16(const void* g, void* l) {
  __builtin_amdgcn_global_load_lds(
      (__attribute__((address_space(1))) void*)g,
      (__attribute__((address_space(3))) void*)l, 16, 0, 0);
}

// Kernel 1: xlen per row + bf16 x, pre-swizzled (byte ^= (row&7)<<4).
__global__ __launch_bounds__(256) void prep_x(const float* __restrict__ x,
                                              unsigned short* __restrict__ x_swz,
                                              float* __restrict__ xlen) {
  int wv = threadIdx.x >> 6, lane = threadIdx.x & 63;
  int row = blockIdx.x * 4 + wv;
  float4 v = *(const float4*)(x + row * D_DIM + lane * 4);
  float ss = v.x * v.x + v.y * v.y + v.z * v.z + v.w * v.w;
#pragma unroll
  for (int m = 1; m < 64; m <<= 1) ss += __shfl_xor(ss, m);
  if (lane == 0) xlen[row] = sqrtf(ss);
  ushort4 u;
  u.x = (unsigned short)f2bf(v.x);
  u.y = (unsigned short)f2bf(v.y);
  u.z = (unsigned short)f2bf(v.z);
  u.w = (unsigned short)f2bf(v.w);
  int byteoff = row * 512 + ((lane * 8) ^ ((row & 7) << 4));
  *(ushort4*)((char*)x_swz + byteoff) = u;
}

// Kernel 2 — FINAL (r18 verbatim, the measured best: 78.0us total).
// Converged structure after 20 rounds of single-variable probes:
//  - grid over N only: 782 blocks x 128 cols, W read exactly once (traffic
//    floor: 102MB R + 205MB W; rows/block=512 keeps amplification at 1x)
//  - 4 waves x 32 cols; fw A-frags register-resident (64 VGPR/wave; 256-col
//    blocks spill or halve occupancy -> regress, r13/r20)
//  - x streamed via global_load_lds, 2x16KB double buffer (L2-resident)
//  - TRANSPOSE EPILOGUE through LDS tb[32][132]: store instructions cover
//    contiguous 512B runs instead of 16 scattered 64B granules (+8us, r15)
//  - NON-TEMPORAL stores: bypass L2 so DRAM sees issue-order runs, not
//    eviction-order scatter (+12us, r17)
//  - lgkm-only transpose barrier + counted vmcnt(4) end-of-chunk barrier:
//    prefetch gloads and nt stores stay in flight across barriers
// Residual gap to the 44us traffic floor is DRAM page-locality on 512B-run
// scattered write streams (~3.4 TB/s isolated ceiling, r19) — forced by the
// op shape (row-major 512x100000 out + VGPR-bounded 128-col block width).
__global__ __launch_bounds__(256) void gemm_bf16(
    const float* __restrict__ W, const unsigned short* __restrict__ xb,
    const float* __restrict__ xlen, float* __restrict__ out) {
  __shared__ unsigned short xs[2][32 * 256];   // 32 KB (swizzled x rows)
  __shared__ float tb[32 * 132];               // 16.5 KB transpose buffer
  __shared__ float xlen_s[B_DIM];              // 2 KB

  const int tid = threadIdx.x;
  const int lane = tid & 63, wv = tid >> 6;
  const int l15 = lane & 15, g = lane >> 4;
  const int bcol0 = blockIdx.x * 128;
  const int bn0 = bcol0 + wv * 32;

  for (int i = tid; i < B_DIM; i += 256) xlen_s[i] = xlen[i];

  // prologue: stage chunk 0
#pragma unroll
  for (int i = 0; i < 4; ++i)
    gload_lds16((const char*)xb + i * 4096 + tid * 16,
                (char*)xs[0] + i * 4096 + wv * 1024);

  // ---- Phase 1: W cols -> A-frags (bf16) + inv_wlen (fp32) ----
  // A-frag: lane holds A[row][k], row = lane&15 -> W-col, k = kg*32+g*8+j.
  bf16x8 fw[2][8];
  float invw4[2][4];   // inv_wlen for W-col = bn0 + it*16 + g*4 + r
#pragma unroll
  for (int it = 0; it < 2; ++it) {
    int col = bn0 + it * 16 + l15;
    if (col >= C_DIM) col = C_DIM - 1;        // clamp; stores are guarded
    const float* wr = W + (size_t)col * D_DIM + g * 8;
    float ss = 0.f;
#pragma unroll
    for (int kg = 0; kg < 8; ++kg) {
      float4 a = *(const float4*)(wr + kg * 32);
      float4 b = *(const float4*)(wr + kg * 32 + 4);
      ss += a.x * a.x + a.y * a.y + a.z * a.z + a.w * a.w
          + b.x * b.x + b.y * b.y + b.z * b.z + b.w * b.w;
      bf16x8 f;
      f[0] = f2bf(a.x); f[1] = f2bf(a.y); f[2] = f2bf(a.z); f[3] = f2bf(a.w);
      f[4] = f2bf(b.x); f[5] = f2bf(b.y); f[6] = f2bf(b.z); f[7] = f2bf(b.w);
      fw[it][kg] = f;
    }
    ss += __shfl_xor(ss, 16);                 // reduce across the 4 g-groups
    ss += __shfl_xor(ss, 32);
    float iw = 1.0f / sqrtf(ss);              // lane l15 holds col bn0+it*16+l15
#pragma unroll
    for (int r = 0; r < 4; ++r) invw4[it][r] = __shfl(iw, g * 4 + r);
  }

  __syncthreads();                            // chunk 0 staged (once; full drain ok)

  // ---- Main loop: 16 chunks of 32 rows ----
  int buf = 0;
  for (int chunk = 0; chunk < 16; ++chunk) {
    if (chunk < 15) {                         // prefetch next chunk
#pragma unroll
      for (int i = 0; i < 4; ++i)
        gload_lds16((const char*)xb + (chunk + 1) * 16384 + i * 4096 + tid * 16,
                    (char*)xs[buf ^ 1] + i * 4096 + wv * 1024);
    }
    __builtin_amdgcn_sched_barrier(0);        // gloads stay above

    // compute the whole 32-row chunk (acc: 16 regs, static-indexed)
    f32x4 acc[2][2] = {};                     // [jtl][it]
#pragma unroll
    for (int jtl = 0; jtl < 2; ++jtl) {
      const char* xp = (const char*)xs[buf] + (jtl * 16 + l15) * 512;
      const int swz = (l15 & 7) << 4;
      bf16x8 fx[8];
#pragma unroll
      for (int kg = 0; kg < 8; ++kg)
        fx[kg] = *(const bf16x8*)(xp + ((kg * 64 + g * 16) ^ swz));
#pragma unroll
      for (int kg = 0; kg < 8; ++kg) {
        acc[jtl][0] = __builtin_amdgcn_mfma_f32_16x16x32_bf16(fw[0][kg], fx[kg], acc[jtl][0], 0, 0, 0);
        acc[jtl][1] = __builtin_amdgcn_mfma_f32_16x16x32_bf16(fw[1][kg], fx[kg], acc[jtl][1], 0, 0, 0);
      }
    }

    // epilogue math + transpose write: tb[lrow][wcol_local] (row pad +4)
#pragma unroll
    for (int jtl = 0; jtl < 2; ++jtl) {
      const int lrow = jtl * 16 + l15;
      const float xl = xlen_s[chunk * 32 + lrow];
#pragma unroll
      for (int it = 0; it < 2; ++it) {
        float4 v;
        v.x = fminf(fmaxf(acc[jtl][it][0] * invw4[it][0], -xl), xl);
        v.y = fminf(fmaxf(acc[jtl][it][1] * invw4[it][1], -xl), xl);
        v.z = fminf(fmaxf(acc[jtl][it][2] * invw4[it][2], -xl), xl);
        v.w = fminf(fmaxf(acc[jtl][it][3] * invw4[it][3], -xl), xl);
        *(float4*)&tb[lrow * 132 + wv * 32 + it * 16 + g * 4] = v;
      }
    }

    // barrier A: LDS-only — prefetch gloads stay in flight (no vmcnt drain)
    asm volatile("s_waitcnt lgkmcnt(0)" ::: "memory");
    __builtin_amdgcn_s_barrier();

    // read back row-contiguous, store 512B runs NON-TEMPORAL (bypass L2)
    {
      const int c16 = tid & 31;               // 16B col unit within 512B row
      const int rbase = tid >> 5;              // 0..7
      const int gcol = bcol0 + c16 * 4;
      const bool ok = gcol < C_DIM;           // C%4==0 -> float4 all-or-nothing
#pragma unroll
      for (int p = 0; p < 4; ++p) {
        const int lrow = p * 8 + rbase;
        f32x4 v = *(const f32x4*)&tb[lrow * 132 + c16 * 4];
        if (ok)
          __builtin_nontemporal_store(
              v, (f32x4*)(out + (size_t)(chunk * 32 + lrow) * C_DIM + gcol));
      }
    }

    // end-of-chunk: counted wait — retire prefetch gloads (oldest), leave
    // this chunk's 4 nt stores in flight. No barrier after the last chunk.
    if (chunk < 15) {
      __builtin_amdgcn_sched_barrier(0);      // stores stay above
      asm volatile("s_waitcnt vmcnt(4)" ::: "memory");
      __builtin_amdgcn_s_barrier();
      __builtin_amdgcn_sched_barrier(0);
    }
    buf ^= 1;
  }
}

// Kernel 3: exact fp32 recompute of the 512 label positions (margin math).
__global__ __launch_bounds__(256) void fix_labels(const float* __restrict__ x,
                                                  const float* __restrict__ W,
                                                  const int* __restrict__ y,
                                                  float* __restrict__ out) {
  int wv = threadIdx.x >> 6, lane = threadIdx.x & 63;
  int b = blockIdx.x * 4 + wv;
  int c = y[b];
  float4 wvv = *(const float4*)(W + (size_t)c * D_DIM + lane * 4);
  float4 xv  = *(const float4*)(x + b * D_DIM + lane * 4);
  float dt = wvv.x * xv.x + wvv.y * xv.y + wvv.z * xv.z + wvv.w * xv.w;
  float sw = wvv.x * wvv.x + wvv.y * wvv.y + wvv.z * wvv.z + wvv.w * wvv.w;
  float sx = xv.x * xv.x + xv.y * xv.y + xv.z * xv.z + xv.w * xv.w;
#pragma unroll
  for (int m = 1; m < 64; m <<= 1) {
    dt += __shfl_xor(dt, m);
    sw += __shfl_xor(sw, m);
    sx += __shfl_xor(sx, m);
  }
  if (lane == 0) {
    float xl = sqrtf(sx), wl = sqrtf(sw);
    float cth = dt / (xl * wl);
    cth = fminf(fmaxf(cth, -1.f), 1.f);
    float c2 = cth * cth;
    float cm = 8.f * c2 * c2 - 8.f * c2 + 1.f;          // cos(4t) Chebyshev
    float k = floorf(4.0f * acosf(cth) / 3.14159265358979323846f);
    float sgn = (((int)k) & 1) ? -1.f : 1.f;
    float phi = sgn * cm - 2.f * k;
    float feat = cth * xl;
    out[(size_t)b * C_DIM + c] = feat + (phi * xl - feat) / (1.f + LAMB);
  }
}

extern "C" void kernel_launch(void* const* d_in, const int* in_sizes, int n_in,
                              void* d_out, int out_size, void* d_ws, size_t ws_size,
                              hipStream_t stream) {
  const float* x = (const float*)d_in[0];
  const float* W = (const float*)d_in[1];
  const int*   y = (const int*)d_in[2];
  float* out = (float*)d_out;

  unsigned short* xb = (unsigned short*)d_ws;                    // 256 KB (swizzled bf16 x)
  float* xlen = (float*)((char*)d_ws + B_DIM * D_DIM * 2);       // 2 KB

  prep_x<<<B_DIM / 4, 256, 0, stream>>>(x, xb, xlen);
  gemm_bf16<<<(C_DIM + 127) / 128, 256, 0, stream>>>(W, xb, xlen, out);
  fix_labels<<<B_DIM / 4, 256, 0, stream>>>(x, W, y, out);
}